// Round 10
// baseline (117.305 us; speedup 1.0000x reference)
//
#include <hip/hip_runtime.h>
#include <hip/hip_bf16.h>

#define TT 2048
#define NB 16
#define FD 128
#define ALPHA 0.2f

typedef __attribute__((ext_vector_type(8))) short short8;
typedef __attribute__((ext_vector_type(4))) float f32x4;
typedef __attribute__((ext_vector_type(16))) float f32x16;

static __device__ __forceinline__ unsigned short f2bf(float f) {
    unsigned u = __float_as_uint(f);
    u += 0x7FFF + ((u >> 16) & 1);          // round-to-nearest-even
    return (unsigned short)(u >> 16);
}
static __device__ __forceinline__ unsigned short bfbits(float f) {
    return __builtin_bit_cast(unsigned short, __float2bfloat16(f));  // HW RNE cvt
}

// Kernel 0: WT[f][k] = bf16(W[k][f])  (128x128, tiny)
__global__ __launch_bounds__(256) void k_wt(const float* __restrict__ W,
                                            unsigned short* __restrict__ WT)
{
    int fid = blockIdx.x * 256 + threadIdx.x;   // 4096 float4s
    int k = fid >> 5;
    int f = (fid & 31) << 2;
    float4 w4 = *reinterpret_cast<const float4*>(W + k * FD + f);
    WT[(f + 0) * FD + k] = f2bf(w4.x);
    WT[(f + 1) * FD + k] = f2bf(w4.y);
    WT[(f + 2) * FD + k] = f2bf(w4.z);
    WT[(f + 3) * FD + k] = f2bf(w4.w);
}

// Kernel 1: h = x@W (bf16 MFMA, WT from L2); write hF fragment-linear for
// mfma_f32_32x32x16_bf16: hF[b][j16][n32][lane][e] with
// j = j16*16 + 8*(lane>>5) + e, f = n32*32 + (lane&31).
// Also s1 = h@a1, s2 = h@a2 (fp32).
__global__ __launch_bounds__(256) void k_h(const float* __restrict__ x,
                                           const unsigned short* __restrict__ WT,
                                           const float* __restrict__ a,
                                           unsigned short* __restrict__ hF,
                                           float* __restrict__ s1,
                                           float* __restrict__ s2)
{
    __shared__ unsigned short hs[128][72];   // h-tile transpose staging (18.4 KB)

    const int tid = threadIdx.x;
    const int b  = blockIdx.x >> 5;
    const int t0 = (blockIdx.x & 31) << 6;
    const int w = tid >> 6, l = tid & 63, g = l >> 4, r15 = l & 15;

    const float* xrow = x + ((size_t)(b * TT + t0 + w * 16 + r15)) * FD;

    f32x4 acc[8] = {};

    #pragma unroll
    for (int m = 0; m < 4; ++m) {
        const int koff = m * 32 + g * 8;
        float4 xa = *reinterpret_cast<const float4*>(xrow + koff);
        float4 xb = *reinterpret_cast<const float4*>(xrow + koff + 4);
        short8 af;
        af[0] = (short)f2bf(xa.x); af[1] = (short)f2bf(xa.y);
        af[2] = (short)f2bf(xa.z); af[3] = (short)f2bf(xa.w);
        af[4] = (short)f2bf(xb.x); af[5] = (short)f2bf(xb.y);
        af[6] = (short)f2bf(xb.z); af[7] = (short)f2bf(xb.w);
        #pragma unroll
        for (int n = 0; n < 8; ++n) {
            short8 bfr = *reinterpret_cast<const short8*>(WT + (n * 16 + r15) * FD + koff);
            acc[n] = __builtin_amdgcn_mfma_f32_16x16x32_bf16(af, bfr, acc[n], 0, 0, 0);
        }
    }

    // s1/s2 from fp32 accumulators: lane holds h[t0+w*16+4g+r][16n+r15]
    float p1[4] = {0.f, 0.f, 0.f, 0.f}, p2[4] = {0.f, 0.f, 0.f, 0.f};
    #pragma unroll
    for (int n = 0; n < 8; ++n) {
        float a1v = a[n * 16 + r15];
        float a2v = a[FD + n * 16 + r15];
        #pragma unroll
        for (int r = 0; r < 4; ++r) {
            p1[r] += acc[n][r] * a1v;
            p2[r] += acc[n][r] * a2v;
        }
    }
    #pragma unroll
    for (int r = 0; r < 4; ++r) {
        #pragma unroll
        for (int off = 8; off >= 1; off >>= 1) {
            p1[r] += __shfl_xor(p1[r], off);
            p2[r] += __shfl_xor(p2[r], off);
        }
    }
    if (r15 == 0) {
        const int trow = t0 + w * 16 + g * 4;
        #pragma unroll
        for (int r = 0; r < 4; ++r) {
            s1[b * TT + trow + r] = p1[r];
            s2[b * TT + trow + r] = p2[r];
        }
    }

    // stage h tile (bf16) transposed: hs[f][t_local]
    #pragma unroll
    for (int n = 0; n < 8; ++n)
        #pragma unroll
        for (int r = 0; r < 4; ++r)
            hs[n * 16 + r15][w * 16 + g * 4 + r] = f2bf(acc[n][r]);
    __syncthreads();

    // write fragment-linear hF: 4 j16-tiles x 4 n32 x 64 lanes x 16B = 16KB
    #pragma unroll
    for (int it = 0; it < 4; ++it) {
        int idx = it * 256 + tid;            // 0..1023
        int lp = idx & 63;                   // consumer lane
        int frag = idx >> 6;                 // 0..15
        int n32 = frag & 3, tl = frag >> 2;  // local j16 tile
        int fsrc = n32 * 32 + (lp & 31);
        int tsrc = tl * 16 + (lp >> 5) * 8;
        short8 v = *reinterpret_cast<const short8*>(&hs[fsrc][tsrc]);
        *reinterpret_cast<short8*>(
            hF + (((size_t)(b * 128 + (t0 >> 4) + tl)) * 4 + n32) * 512 + lp * 8) = v;
    }
}

// Kernel 2: fused mask+softmax+PV, barrier-free main loop, adj read DIRECTLY
// from HBM (single pass over adj — no pack kernel). Block = 32 i-rows, 4 waves
// each owning a 512-j quarter x full f=128. Per 16-j step, each lane loads its
// 32B of adj one step ahead into an explicit register double-buffer (static
// indices under full unroll) — the same proven pattern as the B-frag dbuf —
// so the HBM stream stays in flight while VALU+MFMA run. 12 waves/CU keep
// ~24KB/CU outstanding, ~2.5x what 6.3TB/s needs at ~900cy latency.
__global__ __launch_bounds__(256, 3) void k_att(const int* __restrict__ adj,
                                                const unsigned short* __restrict__ hF,
                                                const float* __restrict__ s1,
                                                const float* __restrict__ s2,
                                                float* __restrict__ out)
{
    __shared__ __align__(16) float red[2][32][132];   // 33.8 KB
    __shared__ float dsum[4][32];

    const int tid = threadIdx.x;
    // bijective XCD swizzle: 1024 blocks = 8 XCDs x 128 contiguous
    const int wg = (blockIdx.x & 7) * 128 + (blockIdx.x >> 3);
    const int b  = wg >> 6;
    const int i0 = (wg & 63) << 5;
    const int w = tid >> 6, l = tid & 63;
    const int il = l & 31, h = l >> 5;        // A row, k-half

    const int jbeg = w * (TT / 4);
    const float s1v = s1[b * TT + i0 + il];
    const float* s2p = s2 + b * TT + jbeg + h * 8;
    const int* adjp = adj + ((size_t)(b * TT + i0 + il)) * TT + jbeg + h * 8;
    const unsigned short* hfp = hF + ((size_t)(b * 128 + (jbeg >> 4))) * 4 * 512 + l * 8;

    f32x16 acc[4] = {};
    float rsum = 0.f;

    short8 bb[2][4];                          // depth-1 B double-buffer (L2)
    #pragma unroll
    for (int n = 0; n < 4; ++n)
        bb[0][n] = *reinterpret_cast<const short8*>(hfp + (size_t)n * 512);

    int4 ar[2][2];                            // depth-1 adj double-buffer (HBM)
    ar[0][0] = *reinterpret_cast<const int4*>(adjp);
    ar[0][1] = *reinterpret_cast<const int4*>(adjp + 4);

    #pragma unroll
    for (int t = 0; t < 32; ++t) {            // 16 j per step
        const int cur = t & 1;
        if (t < 31) {                         // adj prefetch first (longest latency)
            ar[cur ^ 1][0] = *reinterpret_cast<const int4*>(adjp + (t + 1) * 16);
            ar[cur ^ 1][1] = *reinterpret_cast<const int4*>(adjp + (t + 1) * 16 + 4);
            #pragma unroll
            for (int n = 0; n < 4; ++n)       // then B frags (L2)
                bb[cur ^ 1][n] = *reinterpret_cast<const short8*>(
                    hfp + (size_t)((t + 1) * 4 + n) * 512);
        }

        float4 sa = *reinterpret_cast<const float4*>(s2p + t * 16);
        float4 sb = *reinterpret_cast<const float4*>(s2p + t * 16 + 4);
        float csf[8] = {sa.x, sa.y, sa.z, sa.w, sb.x, sb.y, sb.z, sb.w};
        const int ad[8] = {ar[cur][0].x, ar[cur][0].y, ar[cur][0].z, ar[cur][0].w,
                           ar[cur][1].x, ar[cur][1].y, ar[cur][1].z, ar[cur][1].w};
        float pv[8];
        #pragma unroll
        for (int e = 0; e < 8; ++e) {
            float s = s1v + csf[e];
            s = fmaxf(s, ALPHA * s);                     // leaky_relu
            float p = ad[e] ? __expf(s) : 0.f;           // mask
            rsum += p;                                   // denom (unrounded)
            pv[e] = p;
        }
        short8 af;
        #pragma unroll
        for (int e = 0; e < 8; ++e)
            af[e] = (short)bfbits(pv[e]);                // HW RNE cvt
        #pragma unroll
        for (int n = 0; n < 4; ++n)
            acc[n] = __builtin_amdgcn_mfma_f32_32x32x16_bf16(af, bb[cur][n], acc[n], 0, 0, 0);
    }

    // quarter row-sums: combine the two k-halves, store per-wave partials
    rsum += __shfl_xor(rsum, 32);
    if (l < 32) dsum[w][l] = rsum;

    // two-step LDS reduction of the 4 wave-partial accumulators
    if (w < 2) {
        #pragma unroll
        for (int n = 0; n < 4; ++n)
            #pragma unroll
            for (int r = 0; r < 16; ++r) {
                int irow = (r & 3) + 8 * (r >> 2) + 4 * h;
                red[w][irow][n * 32 + il] = acc[n][r];
            }
    }
    __syncthreads();
    if (w >= 2) {
        #pragma unroll
        for (int n = 0; n < 4; ++n)
            #pragma unroll
            for (int r = 0; r < 16; ++r) {
                int irow = (r & 3) + 8 * (r >> 2) + 4 * h;
                red[w - 2][irow][n * 32 + il] += acc[n][r];
            }
    }
    __syncthreads();

    // epilogue: 32 rows x 128 cols = 1024 float4 over 256 threads
    #pragma unroll
    for (int it = 0; it < 4; ++it) {
        int e = it * 256 + tid;
        int row = e >> 5;
        int c4 = (e & 31) << 2;
        float4 v0 = *reinterpret_cast<const float4*>(&red[0][row][c4]);
        float4 v1 = *reinterpret_cast<const float4*>(&red[1][row][c4]);
        float dn = dsum[0][row] + dsum[1][row] + dsum[2][row] + dsum[3][row];
        float ri = 1.0f / dn;
        float4 o;
        o.x = (v0.x + v1.x) * ri;
        o.y = (v0.y + v1.y) * ri;
        o.z = (v0.z + v1.z) * ri;
        o.w = (v0.w + v1.w) * ri;
        *reinterpret_cast<float4*>(out + ((size_t)(b * TT + i0 + row)) * FD + c4) = o;
    }
}

extern "C" void kernel_launch(void* const* d_in, const int* in_sizes, int n_in,
                              void* d_out, int out_size, void* d_ws, size_t ws_size,
                              hipStream_t stream)
{
    const float* x  = (const float*)d_in[0];
    const int* adj  = (const int*)d_in[1];
    const float* W  = (const float*)d_in[2];
    const float* a  = (const float*)d_in[3];
    float* out = (float*)d_out;

    unsigned short* hF = (unsigned short*)d_ws;                       // 8 MB bf16 (fragment-linear)
    float* s1 = (float*)((char*)d_ws + (size_t)NB * FD * TT * 2);
    float* s2 = s1 + NB * TT;
    unsigned short* WT = (unsigned short*)(s2 + NB * TT);             // 32 KB

    k_wt <<<16, 256, 0, stream>>>(W, WT);
    k_h  <<<NB * (TT / 64), 256, 0, stream>>>(x, WT, a, hF, s1, s2);
    k_att<<<NB * (TT / 32), 256, 0, stream>>>(adj, hF, s1, s2, out);
}

// Round 11
// 113.329 us; speedup vs baseline: 1.0351x; 1.0351x over previous
//
#include <hip/hip_runtime.h>
#include <hip/hip_bf16.h>

#define TT 2048
#define NB 16
#define FD 128
#define ALPHA 0.2f

typedef __attribute__((ext_vector_type(8))) short short8;
typedef __attribute__((ext_vector_type(4))) float f32x4;
typedef __attribute__((ext_vector_type(16))) float f32x16;

static __device__ __forceinline__ unsigned short f2bf(float f) {
    unsigned u = __float_as_uint(f);
    u += 0x7FFF + ((u >> 16) & 1);          // round-to-nearest-even
    return (unsigned short)(u >> 16);
}
static __device__ __forceinline__ unsigned short bfbits(float f) {
    return __builtin_bit_cast(unsigned short, __float2bfloat16(f));  // HW RNE cvt
}

// Kernel 0: WT[f][k] = bf16(W[k][f])  (128x128, tiny)
__global__ __launch_bounds__(256) void k_wt(const float* __restrict__ W,
                                            unsigned short* __restrict__ WT)
{
    int fid = blockIdx.x * 256 + threadIdx.x;   // 4096 float4s
    int k = fid >> 5;
    int f = (fid & 31) << 2;
    float4 w4 = *reinterpret_cast<const float4*>(W + k * FD + f);
    WT[(f + 0) * FD + k] = f2bf(w4.x);
    WT[(f + 1) * FD + k] = f2bf(w4.y);
    WT[(f + 2) * FD + k] = f2bf(w4.z);
    WT[(f + 3) * FD + k] = f2bf(w4.w);
}

// Kernel 1: h = x@W (bf16 MFMA, WT from L2); write hF fragment-linear for
// mfma_f32_32x32x16_bf16: hF[b][j16][n32][lane][e] with
// j = j16*16 + 8*(lane>>5) + e, f = n32*32 + (lane&31).
// Also s1 = h@a1, s2 = h@a2 (fp32).
__global__ __launch_bounds__(256) void k_h(const float* __restrict__ x,
                                           const unsigned short* __restrict__ WT,
                                           const float* __restrict__ a,
                                           unsigned short* __restrict__ hF,
                                           float* __restrict__ s1,
                                           float* __restrict__ s2)
{
    __shared__ unsigned short hs[128][72];   // h-tile transpose staging (18.4 KB)

    const int tid = threadIdx.x;
    const int b  = blockIdx.x >> 5;
    const int t0 = (blockIdx.x & 31) << 6;
    const int w = tid >> 6, l = tid & 63, g = l >> 4, r15 = l & 15;

    const float* xrow = x + ((size_t)(b * TT + t0 + w * 16 + r15)) * FD;

    f32x4 acc[8] = {};

    #pragma unroll
    for (int m = 0; m < 4; ++m) {
        const int koff = m * 32 + g * 8;
        float4 xa = *reinterpret_cast<const float4*>(xrow + koff);
        float4 xb = *reinterpret_cast<const float4*>(xrow + koff + 4);
        short8 af;
        af[0] = (short)f2bf(xa.x); af[1] = (short)f2bf(xa.y);
        af[2] = (short)f2bf(xa.z); af[3] = (short)f2bf(xa.w);
        af[4] = (short)f2bf(xb.x); af[5] = (short)f2bf(xb.y);
        af[6] = (short)f2bf(xb.z); af[7] = (short)f2bf(xb.w);
        #pragma unroll
        for (int n = 0; n < 8; ++n) {
            short8 bfr = *reinterpret_cast<const short8*>(WT + (n * 16 + r15) * FD + koff);
            acc[n] = __builtin_amdgcn_mfma_f32_16x16x32_bf16(af, bfr, acc[n], 0, 0, 0);
        }
    }

    // s1/s2 from fp32 accumulators: lane holds h[t0+w*16+4g+r][16n+r15]
    float p1[4] = {0.f, 0.f, 0.f, 0.f}, p2[4] = {0.f, 0.f, 0.f, 0.f};
    #pragma unroll
    for (int n = 0; n < 8; ++n) {
        float a1v = a[n * 16 + r15];
        float a2v = a[FD + n * 16 + r15];
        #pragma unroll
        for (int r = 0; r < 4; ++r) {
            p1[r] += acc[n][r] * a1v;
            p2[r] += acc[n][r] * a2v;
        }
    }
    #pragma unroll
    for (int r = 0; r < 4; ++r) {
        #pragma unroll
        for (int off = 8; off >= 1; off >>= 1) {
            p1[r] += __shfl_xor(p1[r], off);
            p2[r] += __shfl_xor(p2[r], off);
        }
    }
    if (r15 == 0) {
        const int trow = t0 + w * 16 + g * 4;
        #pragma unroll
        for (int r = 0; r < 4; ++r) {
            s1[b * TT + trow + r] = p1[r];
            s2[b * TT + trow + r] = p2[r];
        }
    }

    // stage h tile (bf16) transposed: hs[f][t_local]
    #pragma unroll
    for (int n = 0; n < 8; ++n)
        #pragma unroll
        for (int r = 0; r < 4; ++r)
            hs[n * 16 + r15][w * 16 + g * 4 + r] = f2bf(acc[n][r]);
    __syncthreads();

    // write fragment-linear hF: 4 j16-tiles x 4 n32 x 64 lanes x 16B = 16KB
    #pragma unroll
    for (int it = 0; it < 4; ++it) {
        int idx = it * 256 + tid;            // 0..1023
        int lp = idx & 63;                   // consumer lane
        int frag = idx >> 6;                 // 0..15
        int n32 = frag & 3, tl = frag >> 2;  // local j16 tile
        int fsrc = n32 * 32 + (lp & 31);
        int tsrc = tl * 16 + (lp >> 5) * 8;
        short8 v = *reinterpret_cast<const short8*>(&hs[fsrc][tsrc]);
        *reinterpret_cast<short8*>(
            hF + (((size_t)(b * 128 + (t0 >> 4) + tl)) * 4 + n32) * 512 + lp * 8) = v;
    }
}

// Kernel 2: single-pass fused mask+softmax+PV, barrier-free main loop.
// adj read directly from HBM exactly once. Block = 32 i-rows, 4 waves each
// owning a 512-j quarter x full f=128. ALL three streams (adj HBM, B-frags
// L2, s2 L1) use UNIFIED depth-4 register ring buffers with identical
// per-iteration issue order [adj][B][s2], so in-order vmcnt retirement never
// forces a younger adj load to retire early: every load gets 4 full
// iterations of latency slack. Outstanding adj = 8KB/wave x 8 waves/CU =
// 64KB/CU >> the ~9.2KB needed to sustain ~6.3TB/s at ~900cy latency.
__global__ __launch_bounds__(256, 2) void k_att(const int* __restrict__ adj,
                                                const unsigned short* __restrict__ hF,
                                                const float* __restrict__ s1,
                                                const float* __restrict__ s2,
                                                float* __restrict__ out)
{
    __shared__ __align__(16) float red[2][32][132];   // 33.8 KB
    __shared__ float dsum[4][32];

    const int tid = threadIdx.x;
    // bijective XCD swizzle: 1024 blocks = 8 XCDs x 128 contiguous
    const int wg = (blockIdx.x & 7) * 128 + (blockIdx.x >> 3);
    const int b  = wg >> 6;
    const int i0 = (wg & 63) << 5;
    const int w = tid >> 6, l = tid & 63;
    const int il = l & 31, h = l >> 5;        // A row, k-half

    const int jbeg = w * (TT / 4);
    const float s1v = s1[b * TT + i0 + il];
    const float* s2p = s2 + b * TT + jbeg + h * 8;
    const int* adjp = adj + ((size_t)(b * TT + i0 + il)) * TT + jbeg + h * 8;
    const unsigned short* hfp = hF + ((size_t)(b * 128 + (jbeg >> 4))) * 4 * 512 + l * 8;

    f32x16 acc[4] = {};
    float rsum = 0.f;

    int4   arr[4][2];                         // depth-4 adj ring (HBM)
    short8 brr[4][4];                         // depth-4 B-frag ring (L2)
    float4 srr[4][2];                         // depth-4 s2 ring (L1)

    #pragma unroll
    for (int p = 0; p < 4; ++p) {             // prologue: same order [adj][B][s2]
        arr[p][0] = *reinterpret_cast<const int4*>(adjp + p * 16);
        arr[p][1] = *reinterpret_cast<const int4*>(adjp + p * 16 + 4);
        #pragma unroll
        for (int n = 0; n < 4; ++n)
            brr[p][n] = *reinterpret_cast<const short8*>(hfp + (size_t)(p * 4 + n) * 512);
        srr[p][0] = *reinterpret_cast<const float4*>(s2p + p * 16);
        srr[p][1] = *reinterpret_cast<const float4*>(s2p + p * 16 + 4);
    }

    #pragma unroll
    for (int t = 0; t < 32; ++t) {            // 16 j per step; all indices static
        const int sl = t & 3;

        const int ad[8] = {arr[sl][0].x, arr[sl][0].y, arr[sl][0].z, arr[sl][0].w,
                           arr[sl][1].x, arr[sl][1].y, arr[sl][1].z, arr[sl][1].w};
        float csf[8] = {srr[sl][0].x, srr[sl][0].y, srr[sl][0].z, srr[sl][0].w,
                        srr[sl][1].x, srr[sl][1].y, srr[sl][1].z, srr[sl][1].w};
        float pv[8];
        #pragma unroll
        for (int e = 0; e < 8; ++e) {
            float s = s1v + csf[e];
            s = fmaxf(s, ALPHA * s);                     // leaky_relu
            float p = ad[e] ? __expf(s) : 0.f;           // mask
            rsum += p;                                   // denom (unrounded)
            pv[e] = p;
        }
        short8 af;
        #pragma unroll
        for (int e = 0; e < 8; ++e)
            af[e] = (short)bfbits(pv[e]);                // HW RNE cvt
        #pragma unroll
        for (int n = 0; n < 4; ++n)
            acc[n] = __builtin_amdgcn_mfma_f32_32x32x16_bf16(af, brr[sl][n], acc[n], 0, 0, 0);

        if (t < 28) {                         // refill slot for t+4, order [adj][B][s2]
            arr[sl][0] = *reinterpret_cast<const int4*>(adjp + (t + 4) * 16);
            arr[sl][1] = *reinterpret_cast<const int4*>(adjp + (t + 4) * 16 + 4);
            #pragma unroll
            for (int n = 0; n < 4; ++n)
                brr[sl][n] = *reinterpret_cast<const short8*>(
                    hfp + (size_t)((t + 4) * 4 + n) * 512);
            srr[sl][0] = *reinterpret_cast<const float4*>(s2p + (t + 4) * 16);
            srr[sl][1] = *reinterpret_cast<const float4*>(s2p + (t + 4) * 16 + 4);
        }
    }

    // quarter row-sums: combine the two k-halves, store per-wave partials
    rsum += __shfl_xor(rsum, 32);
    if (l < 32) dsum[w][l] = rsum;

    // two-step LDS reduction of the 4 wave-partial accumulators
    if (w < 2) {
        #pragma unroll
        for (int n = 0; n < 4; ++n)
            #pragma unroll
            for (int r = 0; r < 16; ++r) {
                int irow = (r & 3) + 8 * (r >> 2) + 4 * h;
                red[w][irow][n * 32 + il] = acc[n][r];
            }
    }
    __syncthreads();
    if (w >= 2) {
        #pragma unroll
        for (int n = 0; n < 4; ++n)
            #pragma unroll
            for (int r = 0; r < 16; ++r) {
                int irow = (r & 3) + 8 * (r >> 2) + 4 * h;
                red[w - 2][irow][n * 32 + il] += acc[n][r];
            }
    }
    __syncthreads();

    // epilogue: 32 rows x 128 cols = 1024 float4 over 256 threads
    #pragma unroll
    for (int it = 0; it < 4; ++it) {
        int e = it * 256 + tid;
        int row = e >> 5;
        int c4 = (e & 31) << 2;
        float4 v0 = *reinterpret_cast<const float4*>(&red[0][row][c4]);
        float4 v1 = *reinterpret_cast<const float4*>(&red[1][row][c4]);
        float dn = dsum[0][row] + dsum[1][row] + dsum[2][row] + dsum[3][row];
        float ri = 1.0f / dn;
        float4 o;
        o.x = (v0.x + v1.x) * ri;
        o.y = (v0.y + v1.y) * ri;
        o.z = (v0.z + v1.z) * ri;
        o.w = (v0.w + v1.w) * ri;
        *reinterpret_cast<float4*>(out + ((size_t)(b * TT + i0 + row)) * FD + c4) = o;
    }
}

extern "C" void kernel_launch(void* const* d_in, const int* in_sizes, int n_in,
                              void* d_out, int out_size, void* d_ws, size_t ws_size,
                              hipStream_t stream)
{
    const float* x  = (const float*)d_in[0];
    const int* adj  = (const int*)d_in[1];
    const float* W  = (const float*)d_in[2];
    const float* a  = (const float*)d_in[3];
    float* out = (float*)d_out;

    unsigned short* hF = (unsigned short*)d_ws;                       // 8 MB bf16 (fragment-linear)
    float* s1 = (float*)((char*)d_ws + (size_t)NB * FD * TT * 2);
    float* s2 = s1 + NB * TT;
    unsigned short* WT = (unsigned short*)(s2 + NB * TT);             // 32 KB

    k_wt <<<16, 256, 0, stream>>>(W, WT);
    k_h  <<<NB * (TT / 64), 256, 0, stream>>>(x, WT, a, hF, s1, s2);
    k_att<<<NB * (TT / 32), 256, 0, stream>>>(adj, hF, s1, s2, out);
}